// Round 1
// baseline (2800.256 us; speedup 1.0000x reference)
//
#include <hip/hip_runtime.h>

#define THREADS 256

__global__ __launch_bounds__(THREADS) void msg_kernel(
    const float* __restrict__ node,
    const int*   __restrict__ eidx,
    const float* __restrict__ sh0,
    const float* __restrict__ sh1,
    const float* __restrict__ sh2,
    const float* __restrict__ W,
    float*       __restrict__ out,
    int E)
{
    __shared__ float sW[384];
    for (int t = threadIdx.x; t < 384; t += THREADS) sW[t] = W[t];
    __syncthreads();

    int e = blockIdx.x * THREADS + threadIdx.x;
    if (e >= E) return;

    constexpr float IS3  = 0.57735026918962576f;   // 1/sqrt(3)
    constexpr float IS6  = 0.40824829046386302f;   // 1/sqrt(6)
    constexpr float IS10 = 0.31622776601683794f;   // 1/sqrt(10)
    constexpr float IS30 = 0.18257418583505536f;   // 1/sqrt(30)

    const int src = eidx[e];
    const int tgt = eidx[E + e];

    const float s  = sh0[e];
    const float u0 = sh1[3*e+0], u1 = sh1[3*e+1], u2 = sh1[3*e+2];
    const float q0 = sh2[5*e+0], q1 = sh2[5*e+1], q2 = sh2[5*e+2],
                q3 = sh2[5*e+3], q4 = sh2[5*e+4];

    // (2,1,1) CG contracted with sh2 -> symmetric traceless 3x3
    const float Q00 = -q2*IS30 - q4*IS10;
    const float Q01 =  q1*IS10;
    const float Q02 =  q0*IS10;
    const float Q11 =  2.0f*q2*IS30;
    const float Q12 =  q3*IS10;
    const float Q22 = -q2*IS30 + q4*IS10;

    // gather the 32-float src row (rows are 128B aligned)
    float f[32];
    {
        const float4* nr = (const float4*)(node + (size_t)src * 32);
        #pragma unroll
        for (int i = 0; i < 8; ++i) {
            float4 v = nr[i];
            f[4*i+0]=v.x; f[4*i+1]=v.y; f[4*i+2]=v.z; f[4*i+3]=v.w;
        }
    }

    float msg[32];
    #pragma unroll
    for (int j = 0; j < 32; ++j) msg[j] = 0.0f;

    const float s13 = s * IS3;

    #pragma unroll
    for (int i = 0; i < 8; ++i) {
        const float f0i = f[i];
        const float x = f[8+3*i+0], y = f[8+3*i+1], z = f[8+3*i+2];

        // base tensors for input channel i
        const float c0  = s * f0i;                         // (0,0,0) scalar
        const float c3  = IS3 * (u0*x + u1*y + u2*z);      // (1,1,0) scalar
        const float p2  = IS3 * f0i;                       // (1,0,1) coeff
        const float c1x = s13*x, c1y = s13*y, c1z = s13*z; // (0,1,1)
        const float c2x = p2*u0, c2y = p2*u1, c2z = p2*u2; // (1,0,1)
        const float c4x = IS6*(u1*z - u2*y);               // (1,1,1) cross(u,f1)
        const float c4y = IS6*(u2*x - u0*z);
        const float c4z = IS6*(u0*y - u1*x);
        const float c5x = Q00*x + Q01*y + Q02*z;           // (2,1,1)
        const float c5y = Q01*x + Q11*y + Q12*z;
        const float c5z = Q02*x + Q12*y + Q22*z;

        // W row for this input channel: 6 combos x 8 outputs (LDS broadcast)
        float wr[6][8];
        #pragma unroll
        for (int c = 0; c < 6; ++c) {
            float4 a = *(const float4*)&sW[c*64 + i*8 + 0];
            float4 b = *(const float4*)&sW[c*64 + i*8 + 4];
            wr[c][0]=a.x; wr[c][1]=a.y; wr[c][2]=a.z; wr[c][3]=a.w;
            wr[c][4]=b.x; wr[c][5]=b.y; wr[c][6]=b.z; wr[c][7]=b.w;
        }

        #pragma unroll
        for (int o = 0; o < 8; ++o) {
            msg[o] += wr[0][o]*c0 + wr[3][o]*c3;
            msg[8+3*o+0] += wr[1][o]*c1x + wr[2][o]*c2x + wr[4][o]*c4x + wr[5][o]*c5x;
            msg[8+3*o+1] += wr[1][o]*c1y + wr[2][o]*c2y + wr[4][o]*c4y + wr[5][o]*c5y;
            msg[8+3*o+2] += wr[1][o]*c1z + wr[2][o]*c2z + wr[4][o]*c4z + wr[5][o]*c5z;
        }
    }

    float* orow = out + (size_t)tgt * 32;
    #pragma unroll
    for (int j = 0; j < 32; ++j) unsafeAtomicAdd(orow + j, msg[j]);
}

extern "C" void kernel_launch(void* const* d_in, const int* in_sizes, int n_in,
                              void* d_out, int out_size, void* d_ws, size_t ws_size,
                              hipStream_t stream) {
    const float* node = (const float*)d_in[0];
    const int*   eidx = (const int*)d_in[1];
    const float* sh0  = (const float*)d_in[2];
    const float* sh1  = (const float*)d_in[3];
    const float* sh2  = (const float*)d_in[4];
    const float* W    = (const float*)d_in[5];
    float* out = (float*)d_out;

    const int E = in_sizes[2];   // sh0 has exactly E elements

    hipMemsetAsync(d_out, 0, (size_t)out_size * sizeof(float), stream);

    const int grid = (E + THREADS - 1) / THREADS;
    msg_kernel<<<grid, THREADS, 0, stream>>>(node, eidx, sh0, sh1, sh2, W, out, E);
}

// Round 2
// 453.591 us; speedup vs baseline: 6.1735x; 6.1735x over previous
//
#include <hip/hip_runtime.h>

#define THREADS 256

// ---------------- CSR build ----------------

__global__ __launch_bounds__(THREADS) void k_hist(const int* __restrict__ tgt,
                                                  int* __restrict__ cnt, int E) {
    int e = blockIdx.x * THREADS + threadIdx.x;
    if (e < E) atomicAdd(&cnt[tgt[e]], 1);
}

// per-1024-chunk totals
__global__ __launch_bounds__(THREADS) void k_scan_partial(const int* __restrict__ cnt,
                                                          int* __restrict__ bsum, int N) {
    __shared__ int lds[THREADS];
    int base = blockIdx.x * 1024 + threadIdx.x * 4;
    int s = 0;
    #pragma unroll
    for (int k = 0; k < 4; ++k) { int i = base + k; if (i < N) s += cnt[i]; }
    lds[threadIdx.x] = s; __syncthreads();
    for (int off = THREADS / 2; off > 0; off >>= 1) {
        if (threadIdx.x < off) lds[threadIdx.x] += lds[threadIdx.x + off];
        __syncthreads();
    }
    if (threadIdx.x == 0) bsum[blockIdx.x] = lds[0];
}

// single-block exclusive scan of the block sums (NB <= 1024)
__global__ __launch_bounds__(1024) void k_scan_bsum(int* __restrict__ bsum, int NB) {
    __shared__ int lds[1024];
    int t = threadIdx.x;
    int v = (t < NB) ? bsum[t] : 0;
    lds[t] = v; __syncthreads();
    for (int off = 1; off < 1024; off <<= 1) {
        int x = (t >= off) ? lds[t - off] : 0;
        __syncthreads();
        lds[t] += x;
        __syncthreads();
    }
    if (t < NB) bsum[t] = lds[t] - v;   // exclusive
}

// exclusive scan within each chunk + block offset -> rowptr, cursor
__global__ __launch_bounds__(THREADS) void k_scan_final(int* __restrict__ cnt_cursor,
                                                        const int* __restrict__ bsum,
                                                        int* __restrict__ rowptr,
                                                        int N, int E) {
    __shared__ int lds[THREADS];
    int base = blockIdx.x * 1024 + threadIdx.x * 4;
    int v[4]; int local = 0;
    #pragma unroll
    for (int k = 0; k < 4; ++k) {
        int i = base + k;
        v[k] = (i < N) ? cnt_cursor[i] : 0;
        local += v[k];
    }
    lds[threadIdx.x] = local; __syncthreads();
    for (int off = 1; off < THREADS; off <<= 1) {
        int x = (threadIdx.x >= off) ? lds[threadIdx.x - off] : 0;
        __syncthreads();
        lds[threadIdx.x] += x;
        __syncthreads();
    }
    int p = lds[threadIdx.x] - local + bsum[blockIdx.x];
    #pragma unroll
    for (int k = 0; k < 4; ++k) {
        int i = base + k;
        if (i < N) { rowptr[i] = p; cnt_cursor[i] = p; p += v[k]; }
    }
    if (blockIdx.x == 0 && threadIdx.x == 0) rowptr[N] = E;
}

// ---------------- edge message compute + sorted scatter ----------------

__global__ __launch_bounds__(THREADS) void msg_kernel(
    const float* __restrict__ node,
    const int*   __restrict__ eidx,
    const float* __restrict__ sh0,
    const float* __restrict__ sh1,
    const float* __restrict__ sh2,
    const float* __restrict__ W,
    int*         __restrict__ cursor,
    float*       __restrict__ msgbuf,
    int E)
{
    __shared__ float sW[384];
    for (int t = threadIdx.x; t < 384; t += THREADS) sW[t] = W[t];
    __syncthreads();

    int e = blockIdx.x * THREADS + threadIdx.x;
    if (e >= E) return;

    constexpr float IS3  = 0.57735026918962576f;
    constexpr float IS6  = 0.40824829046386302f;
    constexpr float IS10 = 0.31622776601683794f;
    constexpr float IS30 = 0.18257418583505536f;

    const int src = eidx[e];
    const int tgt = eidx[E + e];

    const float s  = sh0[e];
    const float u0 = sh1[3*e+0], u1 = sh1[3*e+1], u2 = sh1[3*e+2];
    const float q0 = sh2[5*e+0], q1 = sh2[5*e+1], q2 = sh2[5*e+2],
                q3 = sh2[5*e+3], q4 = sh2[5*e+4];

    const float Q00 = -q2*IS30 - q4*IS10;
    const float Q01 =  q1*IS10;
    const float Q02 =  q0*IS10;
    const float Q11 =  2.0f*q2*IS30;
    const float Q12 =  q3*IS10;
    const float Q22 = -q2*IS30 + q4*IS10;

    float f[32];
    {
        const float4* nr = (const float4*)(node + (size_t)src * 32);
        #pragma unroll
        for (int i = 0; i < 8; ++i) {
            float4 v = nr[i];
            f[4*i+0]=v.x; f[4*i+1]=v.y; f[4*i+2]=v.z; f[4*i+3]=v.w;
        }
    }

    float msg[32];
    #pragma unroll
    for (int j = 0; j < 32; ++j) msg[j] = 0.0f;

    const float s13 = s * IS3;

    #pragma unroll
    for (int i = 0; i < 8; ++i) {
        const float f0i = f[i];
        const float x = f[8+3*i+0], y = f[8+3*i+1], z = f[8+3*i+2];

        const float c0  = s * f0i;
        const float c3  = IS3 * (u0*x + u1*y + u2*z);
        const float p2  = IS3 * f0i;
        const float c1x = s13*x, c1y = s13*y, c1z = s13*z;
        const float c2x = p2*u0, c2y = p2*u1, c2z = p2*u2;
        const float c4x = IS6*(u1*z - u2*y);
        const float c4y = IS6*(u2*x - u0*z);
        const float c4z = IS6*(u0*y - u1*x);
        const float c5x = Q00*x + Q01*y + Q02*z;
        const float c5y = Q01*x + Q11*y + Q12*z;
        const float c5z = Q02*x + Q12*y + Q22*z;

        float wr[6][8];
        #pragma unroll
        for (int c = 0; c < 6; ++c) {
            float4 a = *(const float4*)&sW[c*64 + i*8 + 0];
            float4 b = *(const float4*)&sW[c*64 + i*8 + 4];
            wr[c][0]=a.x; wr[c][1]=a.y; wr[c][2]=a.z; wr[c][3]=a.w;
            wr[c][4]=b.x; wr[c][5]=b.y; wr[c][6]=b.z; wr[c][7]=b.w;
        }

        #pragma unroll
        for (int o = 0; o < 8; ++o) {
            msg[o] += wr[0][o]*c0 + wr[3][o]*c3;
            msg[8+3*o+0] += wr[1][o]*c1x + wr[2][o]*c2x + wr[4][o]*c4x + wr[5][o]*c5x;
            msg[8+3*o+1] += wr[1][o]*c1y + wr[2][o]*c2y + wr[4][o]*c4y + wr[5][o]*c5y;
            msg[8+3*o+2] += wr[1][o]*c1z + wr[2][o]*c2z + wr[4][o]*c4z + wr[5][o]*c5z;
        }
    }

    const int pos = atomicAdd(&cursor[tgt], 1);
    float4* mr = (float4*)(msgbuf + (size_t)pos * 32);
    #pragma unroll
    for (int i = 0; i < 8; ++i) {
        mr[i] = make_float4(msg[4*i+0], msg[4*i+1], msg[4*i+2], msg[4*i+3]);
    }
}

// ---------------- segment aggregation (no atomics) ----------------

__global__ __launch_bounds__(THREADS) void k_agg(const float* __restrict__ msgbuf,
                                                 const int* __restrict__ rowptr,
                                                 float* __restrict__ out, int N) {
    int gid = blockIdx.x * THREADS + threadIdx.x;
    int n = gid >> 3;
    int t = gid & 7;
    if (n >= N) return;
    int s  = rowptr[n];
    int e2 = rowptr[n + 1];
    float4 acc = make_float4(0.f, 0.f, 0.f, 0.f);
    for (int j = s; j < e2; ++j) {
        float4 v = *(const float4*)(msgbuf + (size_t)j * 32 + t * 4);
        acc.x += v.x; acc.y += v.y; acc.z += v.z; acc.w += v.w;
    }
    *(float4*)(out + (size_t)n * 32 + t * 4) = acc;
}

// ---------------- fallback: round-1 atomic kernel ----------------

__global__ __launch_bounds__(THREADS) void msg_kernel_atomic(
    const float* __restrict__ node,
    const int*   __restrict__ eidx,
    const float* __restrict__ sh0,
    const float* __restrict__ sh1,
    const float* __restrict__ sh2,
    const float* __restrict__ W,
    float*       __restrict__ out,
    int E)
{
    __shared__ float sW[384];
    for (int t = threadIdx.x; t < 384; t += THREADS) sW[t] = W[t];
    __syncthreads();

    int e = blockIdx.x * THREADS + threadIdx.x;
    if (e >= E) return;

    constexpr float IS3  = 0.57735026918962576f;
    constexpr float IS6  = 0.40824829046386302f;
    constexpr float IS10 = 0.31622776601683794f;
    constexpr float IS30 = 0.18257418583505536f;

    const int src = eidx[e];
    const int tgt = eidx[E + e];

    const float s  = sh0[e];
    const float u0 = sh1[3*e+0], u1 = sh1[3*e+1], u2 = sh1[3*e+2];
    const float q0 = sh2[5*e+0], q1 = sh2[5*e+1], q2 = sh2[5*e+2],
                q3 = sh2[5*e+3], q4 = sh2[5*e+4];

    const float Q00 = -q2*IS30 - q4*IS10;
    const float Q01 =  q1*IS10;
    const float Q02 =  q0*IS10;
    const float Q11 =  2.0f*q2*IS30;
    const float Q12 =  q3*IS10;
    const float Q22 = -q2*IS30 + q4*IS10;

    float f[32];
    {
        const float4* nr = (const float4*)(node + (size_t)src * 32);
        #pragma unroll
        for (int i = 0; i < 8; ++i) {
            float4 v = nr[i];
            f[4*i+0]=v.x; f[4*i+1]=v.y; f[4*i+2]=v.z; f[4*i+3]=v.w;
        }
    }

    float msg[32];
    #pragma unroll
    for (int j = 0; j < 32; ++j) msg[j] = 0.0f;

    const float s13 = s * IS3;

    #pragma unroll
    for (int i = 0; i < 8; ++i) {
        const float f0i = f[i];
        const float x = f[8+3*i+0], y = f[8+3*i+1], z = f[8+3*i+2];
        const float c0  = s * f0i;
        const float c3  = IS3 * (u0*x + u1*y + u2*z);
        const float p2  = IS3 * f0i;
        const float c1x = s13*x, c1y = s13*y, c1z = s13*z;
        const float c2x = p2*u0, c2y = p2*u1, c2z = p2*u2;
        const float c4x = IS6*(u1*z - u2*y);
        const float c4y = IS6*(u2*x - u0*z);
        const float c4z = IS6*(u0*y - u1*x);
        const float c5x = Q00*x + Q01*y + Q02*z;
        const float c5y = Q01*x + Q11*y + Q12*z;
        const float c5z = Q02*x + Q12*y + Q22*z;

        float wr[6][8];
        #pragma unroll
        for (int c = 0; c < 6; ++c) {
            float4 a = *(const float4*)&sW[c*64 + i*8 + 0];
            float4 b = *(const float4*)&sW[c*64 + i*8 + 4];
            wr[c][0]=a.x; wr[c][1]=a.y; wr[c][2]=a.z; wr[c][3]=a.w;
            wr[c][4]=b.x; wr[c][5]=b.y; wr[c][6]=b.z; wr[c][7]=b.w;
        }

        #pragma unroll
        for (int o = 0; o < 8; ++o) {
            msg[o] += wr[0][o]*c0 + wr[3][o]*c3;
            msg[8+3*o+0] += wr[1][o]*c1x + wr[2][o]*c2x + wr[4][o]*c4x + wr[5][o]*c5x;
            msg[8+3*o+1] += wr[1][o]*c1y + wr[2][o]*c2y + wr[4][o]*c4y + wr[5][o]*c5y;
            msg[8+3*o+2] += wr[1][o]*c1z + wr[2][o]*c2z + wr[4][o]*c4z + wr[5][o]*c5z;
        }
    }

    float* orow = out + (size_t)tgt * 32;
    #pragma unroll
    for (int j = 0; j < 32; ++j) unsafeAtomicAdd(orow + j, msg[j]);
}

// ---------------- host ----------------

extern "C" void kernel_launch(void* const* d_in, const int* in_sizes, int n_in,
                              void* d_out, int out_size, void* d_ws, size_t ws_size,
                              hipStream_t stream) {
    const float* node = (const float*)d_in[0];
    const int*   eidx = (const int*)d_in[1];
    const float* sh0  = (const float*)d_in[2];
    const float* sh1  = (const float*)d_in[3];
    const float* sh2  = (const float*)d_in[4];
    const float* W    = (const float*)d_in[5];
    float* out = (float*)d_out;

    const int E = in_sizes[2];          // sh0 has E elements
    const int N = in_sizes[0] / 32;     // node_irreps is [N, 32]

    const int NB = (N + 1023) / 1024;   // scan chunks (<= 1024 required)

    // ws layout: rowptr[N+1] | cursor/cnt[N] | bsum[1024] | pad | msg[E*32]
    size_t int_words = (size_t)(N + 1) + N + 1024;
    size_t msg_off_w = (int_words + 3) & ~(size_t)3;        // 16B-align msg
    size_t need = (msg_off_w + (size_t)E * 32) * sizeof(float);

    if (ws_size >= need && NB <= 1024) {
        int* rowptr = (int*)d_ws;
        int* cursor = rowptr + (N + 1);
        int* bsum   = cursor + N;
        float* msgbuf = (float*)d_ws + msg_off_w;

        hipMemsetAsync(cursor, 0, (size_t)N * sizeof(int), stream);

        k_hist<<<(E + THREADS - 1) / THREADS, THREADS, 0, stream>>>(eidx + E, cursor, E);
        k_scan_partial<<<NB, THREADS, 0, stream>>>(cursor, bsum, N);
        k_scan_bsum<<<1, 1024, 0, stream>>>(bsum, NB);
        k_scan_final<<<NB, THREADS, 0, stream>>>(cursor, bsum, rowptr, N, E);

        msg_kernel<<<(E + THREADS - 1) / THREADS, THREADS, 0, stream>>>(
            node, eidx, sh0, sh1, sh2, W, cursor, msgbuf, E);

        k_agg<<<((N * 8) + THREADS - 1) / THREADS, THREADS, 0, stream>>>(
            msgbuf, rowptr, out, N);
    } else {
        hipMemsetAsync(d_out, 0, (size_t)out_size * sizeof(float), stream);
        msg_kernel_atomic<<<(E + THREADS - 1) / THREADS, THREADS, 0, stream>>>(
            node, eidx, sh0, sh1, sh2, W, out, E);
    }
}